// Round 13
// baseline (252.378 us; speedup 1.0000x reference)
//
#include <hip/hip_runtime.h>

#define B_ 8
#define Q_ 512
#define M_ 512
#define R_ 1024
#define H_ 16
#define S_ 64
#define D_ 1024
#define MEG 1048576L

typedef unsigned short ushort_t;
typedef __attribute__((ext_vector_type(8))) _Float16 f16x8;
typedef __attribute__((ext_vector_type(8))) unsigned short u16x8;
typedef __attribute__((ext_vector_type(4))) unsigned short u16x4;
typedef __attribute__((ext_vector_type(4))) float f32x4;
typedef __attribute__((ext_vector_type(2))) unsigned int u32x2;

__device__ __forceinline__ unsigned short h2u(_Float16 h) {
    union { _Float16 h; unsigned short u; } v; v.h = h; return v.u;
}
__device__ __forceinline__ unsigned int pk_f16(float a, float b) {
    union { _Float16 h[2]; unsigned int u; } v;
    v.h[0] = (_Float16)a; v.h[1] = (_Float16)b; return v.u;
}
__device__ __forceinline__ void async_cp16(const ushort_t* g, ushort_t* l) {
    __builtin_amdgcn_global_load_lds(
        (const __attribute__((address_space(1))) void*)g,
        (__attribute__((address_space(3))) void*)l, 16, 0, 0);
}

__global__ __launch_bounds__(256) void zero_out_f32_k(float* __restrict__ p, int n) {
    int i = blockIdx.x * 256 + threadIdx.x;
    if (i < n) p[i] = 0.f;
}

// ---- fused prep: weight transposes (y<5), qcat convert (y in [5,13)),
// ---- pos convert (y==13), bias convert (y==14) ----
__global__ __launch_bounds__(256) void prep_k(
    const float* __restrict__ mem, const float* __restrict__ qry,
    const float* __restrict__ pos, const float* __restrict__ cb,
    const float* __restrict__ pb,
    const float* __restrict__ Wkc, const float* __restrict__ Wv,
    const float* __restrict__ Wkp, const float* __restrict__ Wq,
    const float* __restrict__ Wo,
    ushort_t* __restrict__ qcat, ushort_t* __restrict__ posb,
    ushort_t* __restrict__ cbpb, ushort_t* __restrict__ BT4,
    ushort_t* __restrict__ WoT) {
    int x = blockIdx.x, y = blockIdx.y, t = threadIdx.x;
    if (y < 5) {   // weight transpose: fp32 W[k][n] -> f16 W^T[n][k]
        const float* in; ushort_t* out;
        switch (y) {
            case 0: in = Wkc; out = BT4;           break;
            case 1: in = Wv;  out = BT4 + MEG;     break;
            case 2: in = Wkp; out = BT4 + 2 * MEG; break;
            case 3: in = Wq;  out = BT4 + 3 * MEG; break;
            default: in = Wo; out = WoT;           break;
        }
        __shared__ ushort_t tile[32][33];
        int bx = (x & 31) * 32, by = (x >> 5) * 32;
        int tx = t & 31, ty = t >> 5;
        #pragma unroll
        for (int i = 0; i < 32; i += 8)
            tile[ty + i][tx] = h2u((_Float16)in[(long)(by + ty + i) * 1024 + bx + tx]);
        __syncthreads();
        #pragma unroll
        for (int i = 0; i < 32; i += 8)
            out[(long)(bx + ty + i) * 1024 + by + tx] = tile[tx][ty + i];
    } else if (y < 13) {  // qcat rows: batch g, row r
        int g = y - 5, r = x;
        const float* src = (r < 512) ? (mem + ((long)g * 512 + r) * 1024)
                                     : (qry + ((long)g * 512 + (r - 512)) * 1024);
        ushort_t* dst = qcat + ((long)g * 1024 + r) * 1024;
        int i = t * 4;
        f32x4 v = *(const f32x4*)(src + i);
        u32x2 o; o[0] = pk_f16(v[0], v[1]); o[1] = pk_f16(v[2], v[3]);
        *(u32x2*)(dst + i) = o;
    } else if (y == 13) { // pos rows
        int i = t * 4;
        f32x4 v = *(const f32x4*)(pos + (long)x * 1024 + i);
        u32x2 o; o[0] = pk_f16(v[0], v[1]); o[1] = pk_f16(v[2], v[3]);
        *(u32x2*)(posb + (long)x * 1024 + i) = o;
    } else {              // biases (x==0 only)
        if (x == 0) {
            for (int i = t; i < 1024; i += 256) {
                cbpb[i]        = h2u((_Float16)cb[i]);
                cbpb[1024 + i] = h2u((_Float16)pb[i]);
            }
        }
    }
}

// ---- GEMM body: 128x128 tile, K=1024, f16 MFMA, BK=64 double-buffered LDS,
// ---- 2-phase schedule (STAGE(next) -> ds_read(cur) -> MFMA -> __syncthreads),
// ---- T2 XOR swizzle (rule #21, both-sides involution):
//   LDS per buf: [128 rows][64 elems] linear (128B rows).
//   Stage (write side): thread t, issue i covers row i*32+(t>>3); SOURCE col
//     pre-swizzled gcol = ((t&7)*8) ^ (((t>>3)&7)<<3), so
//     LDS[row][c] = global[row][c ^ ((row&7)<<3)].
//   Read side: col (ks*32+quad*8) ^ ((l16&7)<<3) -> returns global[row][k].
//   Bank math: dword col = base ^ ((row&7)<<2) -> 8 distinct 4-dword groups
//   x 2 lanes = 2-way conflict (free, m136). Old 64B-row layout was 8-way.
// BK=64 halves barrier-drain count (16 vs 32) and doubles compute cover per
// drain (16 ds_read + 32 MFMA > L2 latency). Structure otherwise identical
// to the proven r7 body (no raw barriers / counted vmcnt / multi-buf).
// mode 0: f16 store, row stride crs.  mode 1: f32 store, stride crs.
// mode 2: f16 transposed store into vT: addr = n_local*1024 + m_local.
__device__ __forceinline__ void gemm_body(const ushort_t* Arow0,
                                          const ushort_t* BTrow0,
                                          void* Crow0, long crs, int mode) {
    __shared__ __align__(16) ushort_t Al[2][128 * 64];   // 32 KB
    __shared__ __align__(16) ushort_t Bl[2][128 * 64];   // 32 KB

    int t = threadIdx.x;
    int wave = t >> 6, lane = t & 63, quad = lane >> 4, l16 = lane & 15;
    int wm = (wave & 1) * 64, wn = (wave >> 1) * 64;

    f32x4 acc[4][4];
    #pragma unroll
    for (int im = 0; im < 4; ++im)
        #pragma unroll
        for (int in = 0; in < 4; ++in) acc[im][in] = (f32x4){0.f, 0.f, 0.f, 0.f};

    // staging bases: issue i (0..3) covers rows [i*32, i*32+32);
    // thread t -> row i*32 + (t>>3), pre-swizzled source col.
    int gcol = ((t & 7) * 8) ^ (((t >> 3) & 7) << 3);
    const ushort_t* gA = Arow0 + (long)(t >> 3) * 1024 + gcol;
    const ushort_t* gB = BTrow0 + (long)(t >> 3) * 1024 + gcol;
    int lo = wave * 512;   // wave-uniform LDS base; HW adds lane*16B

#define STAGE(BUF, KOFF) do {                                          \
    async_cp16(gA + 0 * 32768 + (KOFF), &Al[BUF][lo + 0 * 2048]);      \
    async_cp16(gA + 1 * 32768 + (KOFF), &Al[BUF][lo + 1 * 2048]);      \
    async_cp16(gA + 2 * 32768 + (KOFF), &Al[BUF][lo + 2 * 2048]);      \
    async_cp16(gA + 3 * 32768 + (KOFF), &Al[BUF][lo + 3 * 2048]);      \
    async_cp16(gB + 0 * 32768 + (KOFF), &Bl[BUF][lo + 0 * 2048]);      \
    async_cp16(gB + 1 * 32768 + (KOFF), &Bl[BUF][lo + 1 * 2048]);      \
    async_cp16(gB + 2 * 32768 + (KOFF), &Bl[BUF][lo + 2 * 2048]);      \
    async_cp16(gB + 3 * 32768 + (KOFF), &Bl[BUF][lo + 3 * 2048]);      \
} while (0)

    // prologue: stage k-tile 0 into buf 0; __syncthreads drains vmcnt(0)
    STAGE(0, 0);
    __syncthreads();

    int rswz = (l16 & 7) << 3;
    int cur = 0;
    for (int k0 = 0; k0 < 1024; k0 += 64) {
        int nxt = cur ^ 1;
        if (k0 + 64 < 1024) STAGE(nxt, k0 + 64);   // issue next-tile loads FIRST

        #pragma unroll
        for (int ks = 0; ks < 2; ++ks) {
            int rc = (ks * 32 + quad * 8) ^ rswz;
            f16x8 af[4], bf[4];
            #pragma unroll
            for (int im = 0; im < 4; ++im)
                af[im] = *(const f16x8*)&Al[cur][(wm + im * 16 + l16) * 64 + rc];
            #pragma unroll
            for (int in = 0; in < 4; ++in)
                bf[in] = *(const f16x8*)&Bl[cur][(wn + in * 16 + l16) * 64 + rc];
            __builtin_amdgcn_s_setprio(1);
            #pragma unroll
            for (int im = 0; im < 4; ++im)
                #pragma unroll
                for (int in = 0; in < 4; ++in)
                    acc[im][in] = __builtin_amdgcn_mfma_f32_16x16x32_f16(
                        af[im], bf[in], acc[im][in], 0, 0, 0);
            __builtin_amdgcn_s_setprio(0);
        }
        __syncthreads();   // drains this step's staging; next buf ready
        cur = nxt;
    }
#undef STAGE

    if (mode == 2) {   // transposed store (v -> vT): rows = n (hs), cols = m (r)
        #pragma unroll
        for (int im = 0; im < 4; ++im)
            #pragma unroll
            for (int in = 0; in < 4; ++in) {
                u16x4 pk;
                #pragma unroll
                for (int reg = 0; reg < 4; ++reg) pk[reg] = h2u((_Float16)acc[im][in][reg]);
                long addr = (long)(wn + in * 16 + l16) * 1024 + wm + im * 16 + quad * 4;
                *(u16x4*)((ushort_t*)Crow0 + addr) = pk;
            }
        return;
    }
    #pragma unroll
    for (int im = 0; im < 4; ++im)
        #pragma unroll
        for (int in = 0; in < 4; ++in)
            #pragma unroll
            for (int reg = 0; reg < 4; ++reg) {
                long addr = (long)(wm + im * 16 + quad * 4 + reg) * crs
                          + wn + in * 16 + l16;
                if (mode == 1) ((float*)Crow0)[addr] = acc[im][in][reg];
                else ((ushort_t*)Crow0)[addr] = h2u((_Float16)acc[im][in][reg]);
            }
}

// ---- mega projection GEMM, flat grid of exactly 1344 tiles:
// ---- [0,1024): kc/vT (z=id>>7, tl=id&127, x=tl>>4, y=tl&15)
// ---- [1024,1088): kp.  [1088,1344): qproj.
// XCD mapping: id%8 = y&7 -> each XCD holds 2 B-panels (0.5 MB) + A-slice (2 MB) in L2.
__global__ __launch_bounds__(256) void gemm_mega(
    const ushort_t* __restrict__ qcat, const ushort_t* __restrict__ posb,
    const ushort_t* __restrict__ BT4,
    ushort_t* __restrict__ kcC, ushort_t* __restrict__ vT,
    ushort_t* __restrict__ qproj, ushort_t* __restrict__ kpp) {
    int id = blockIdx.x;
    if (id < 1024) {
        int z = id >> 7, tl = id & 127;
        int x = tl >> 4, y = tl & 15;
        const ushort_t* Arow0 = qcat + (long)z * MEG + (long)x * 128 * 1024;
        if (y < 8) {        // kc: dense [B,R,1024]
            gemm_body(Arow0, BT4 + (long)y * 128 * 1024,
                      kcC + (long)z * MEG + (long)x * 128 * 1024 + y * 128, 1024, 0);
        } else {            // v: store transposed into vT [B,1024(hs),1024(r)]
            int n0 = (y - 8) * 128;
            gemm_body(Arow0, BT4 + (long)(1024 + n0) * 1024,
                      vT + ((long)z * 1024 + n0) * 1024 + x * 128, 0, 2);
        }
    } else if (id < 1088) { // kp = posb @ Wkp
        int u = id - 1024;
        int x = u >> 3, y = u & 7;
        gemm_body(posb + (long)x * 128 * 1024,
                  BT4 + (long)(2048 + y * 128) * 1024,
                  kpp + (long)x * 128 * 1024 + y * 128, 1024, 0);
    } else {                // qproj[b] = qcat[b][512..1023] @ Wq
        int u = id - 1088;
        int b = u >> 5, v2 = u & 31;
        int x = v2 >> 3, y = v2 & 7;
        gemm_body(qcat + (long)b * MEG + (long)(512 + x * 128) * 1024,
                  BT4 + (long)(3072 + y * 128) * 1024,
                  qproj + (long)b * 512 * 1024 + (long)x * 128 * 1024 + y * 128, 1024, 0);
    }
}

__global__ __launch_bounds__(256) void gemm_fin(
    const ushort_t* __restrict__ A, const ushort_t* __restrict__ WoT,
    float* __restrict__ out) {
    gemm_body(A + (long)blockIdx.x * 128 * 1024,
              WoT + (long)blockIdx.y * 128 * 1024,
              out + (long)blockIdx.x * 128 * 1024 + blockIdx.y * 128, 1024, 1);
}

// ---- fused relative attention: 128-q-tile, 8 waves, software-pipelined staging ----
// LDS: Kc 9216 + Vt 9216 + Kp 27648 + Pu 18432 = 64512 B -> 2 blocks/CU.
// Row-sum via ones-MFMA; defer-max with thread-local check (shfl reduce rare).
__global__ __launch_bounds__(512) void attn_kernel(
    const ushort_t* __restrict__ qproj,  // [B,Q,1024] f16
    const ushort_t* __restrict__ kc,     // [B,R,1024] f16 (dense)
    const ushort_t* __restrict__ kp,     // [R,1024] f16
    const ushort_t* __restrict__ vT,     // [B,1024,R] f16
    const ushort_t* __restrict__ cbpb,   // [2,16,64] f16
    ushort_t* __restrict__ aout)         // [B,Q,1024] f16 (aliases qproj; safe)
{
    // load-balance swizzle: co-resident blocks (ID, ID+256) -> classes (c, c+2)
    int qt = (blockIdx.x + ((blockIdx.y >> 6) << 1)) & 3;
    int q0 = qt * 128;
    int bh = blockIdx.y;
    int b = bh >> 4, h = bh & 15;
    int t = threadIdx.x;
    int wave = t >> 6, lane = t & 63, quad = lane >> 4, l16 = lane & 15;

    __shared__ __align__(16) ushort_t Kc[64][72];
    __shared__ __align__(16) ushort_t Vt[64][72];
    __shared__ __align__(16) ushort_t Kp[192][72];   // 12 circular 16-row blocks
    __shared__ __align__(16) char Pu[8][2304];       // Pl[16][72] u16 per wave
    ushort_t* Pl = (ushort_t*)&Pu[wave][0];

    const ushort_t* qrow = qproj + ((long)(b * Q_ + q0 + wave * 16 + l16)) * 1024 + h * 64;
    f16x8 qcf[2], qpf[2];
    #pragma unroll
    for (int ks = 0; ks < 2; ++ks) {
        f16x8 qv  = *(const f16x8*)(qrow + ks * 32 + quad * 8);
        f16x8 cbv = *(const f16x8*)(cbpb + h * 64 + ks * 32 + quad * 8);
        f16x8 pbv = *(const f16x8*)(cbpb + 1024 + h * 64 + ks * 32 + quad * 8);
        qcf[ks] = qv + cbv;
        qpf[ks] = qv + pbv;
    }

    float m_s[4];
    f32x4 o_acc[4], ls4;
    #pragma unroll
    for (int r = 0; r < 4; ++r) {
        m_s[r] = -1e30f;
        o_acc[r] = (f32x4){0.f, 0.f, 0.f, 0.f};
    }
    ls4 = (f32x4){0.f, 0.f, 0.f, 0.f};

    f16x8 ones;
    #pragma unroll
    for (int j = 0; j < 8; ++j) ones[j] = (_Float16)1.0f;

    int srow = t >> 3, sc0 = (t & 7) * 8;
    const ushort_t* kcb = kc + ((long)(b * R_) + srow) * 1024 + h * 64 + sc0;
    const ushort_t* vtb = vT + ((long)(b * 1024 + h * 64 + srow)) * 1024 + sc0;
    const ushort_t* kpb = kp + h * 64 + sc0;

    int ntiles = ((q0 + 639) >> 6) + 1;  // causal: last q-row attends r <= q0+639

    // pipeline prologue: iter-0 staging in registers
    u16x8 rKc = *(const u16x8*)(kcb);
    u16x8 rVt = *(const u16x8*)(vtb);
    u16x8 rKp[3];
    {
        int jb0 = 384 - q0;
        #pragma unroll
        for (int p = 0; p < 3; ++p) {
            int j = jb0 + p * 64 + srow;
            int jc = j > 1023 ? 1023 : j;
            rKp[p] = *(const u16x8*)(kpb + (long)jc * 1024);
        }
    }

    for (int it = 0; it < ntiles; ++it) {
        int r0 = it * 64;
        int jbase = r0 - q0 + 384;
        int gb0 = jbase >> 4;
        __syncthreads();
        *(u16x8*)&Kc[srow][sc0] = rKc;
        *(u16x8*)&Vt[srow][sc0] = rVt;
        if (it == 0) {
            #pragma unroll
            for (int p = 0; p < 3; ++p) {
                int j = jbase + p * 64 + srow;
                int ph = ((j >> 4) % 12) * 16 + (j & 15);
                *(u16x8*)&Kp[ph][sc0] = rKp[p];
            }
        } else {
            int j = jbase + 128 + srow;
            int ph = ((j >> 4) % 12) * 16 + (j & 15);
            *(u16x8*)&Kp[ph][sc0] = rKp[0];
        }
        __syncthreads();
        if (it + 1 < ntiles) {
            int r1 = r0 + 64;
            rKc = *(const u16x8*)(kcb + (long)r1 * 1024);
            rVt = *(const u16x8*)(vtb + r1);
            int j = r1 - q0 + 512 + srow;
            int jc = j > 1023 ? 1023 : j;
            rKp[0] = *(const u16x8*)(kpb + (long)jc * 1024);
        }

        f32x4 sc[4];
        #pragma unroll
        for (int s = 0; s < 4; ++s) sc[s] = (f32x4){0.f, 0.f, 0.f, 0.f};
        f32x4 dd[5];
        #pragma unroll
        for (int s = 0; s < 5; ++s) dd[s] = (f32x4){0.f, 0.f, 0.f, 0.f};

        __builtin_amdgcn_s_setprio(1);
        #pragma unroll
        for (int ks = 0; ks < 2; ++ks)
            #pragma unroll
            for (int sub = 0; sub < 4; ++sub) {
                f16x8 bb = *(const f16x8*)&Kc[sub * 16 + l16][ks * 32 + quad * 8];
                sc[sub] = __builtin_amdgcn_mfma_f32_16x16x32_f16(qcf[ks], bb, sc[sub], 0, 0, 0);
            }
        #pragma unroll
        for (int ks = 0; ks < 2; ++ks)
            #pragma unroll
            for (int sub = 0; sub < 5; ++sub) {
                int pb = (gb0 + 7 - wave + sub) % 12;
                f16x8 bb = *(const f16x8*)&Kp[pb * 16 + l16][ks * 32 + quad * 8];
                dd[sub] = __builtin_amdgcn_mfma_f32_16x16x32_f16(qpf[ks], bb, dd[sub], 0, 0, 0);
            }
        __builtin_amdgcn_s_setprio(0);

        // rel-shift diagonal extraction IN-REGISTER (proven r1-r11).
        #pragma unroll
        for (int reg = 0; reg < 4; ++reg) {
            int row16 = quad * 4 + reg;
            int src = (lane & 48) + ((l16 + 15 - row16) & 15);
            float dsh[5];
            #pragma unroll
            for (int sub = 0; sub < 5; ++sub)
                dsh[sub] = __shfl(dd[sub][reg], src);
            #pragma unroll
            for (int sub = 0; sub < 4; ++sub) {
                float dval = (l16 > row16) ? dsh[sub + 1] : dsh[sub];
                float sv = (sc[sub][reg] + dval) * 0.125f;
                int rl = sub * 16 + l16;
                if (r0 + rl > q0 + wave * 16 + row16 + 512) sv = -1e30f;
                sc[sub][reg] = sv;
            }
        }

        // T13 defer-max with CHEAP check (shfl reduce only on rare fail path).
        float vmax[4];
        #pragma unroll
        for (int reg = 0; reg < 4; ++reg)
            vmax[reg] = fmaxf(fmaxf(sc[0][reg], sc[1][reg]),
                              fmaxf(sc[2][reg], sc[3][reg]));
        int ok = (vmax[0] <= m_s[0] + 8.f) & (vmax[1] <= m_s[1] + 8.f) &
                 (vmax[2] <= m_s[2] + 8.f) & (vmax[3] <= m_s[3] + 8.f);
        if (!__all(ok)) {
            #pragma unroll
            for (int reg = 0; reg < 4; ++reg) {
                float rm = vmax[reg];
                #pragma unroll
                for (int m = 1; m < 16; m <<= 1) rm = fmaxf(rm, __shfl_xor(rm, m));
                float mn = fmaxf(m_s[reg], rm);
                float alpha = __expf(m_s[reg] - mn);
                m_s[reg] = mn;
                ls4[reg] *= alpha;
                #pragma unroll
                for (int sub = 0; sub < 4; ++sub)
                    o_acc[sub][reg] *= alpha;
            }
        }
        #pragma unroll
        for (int sub = 0; sub < 4; ++sub)
            #pragma unroll
            for (int reg = 0; reg < 4; ++reg) {
                float p = __expf(sc[sub][reg] - m_s[reg]);
                Pl[(quad * 4 + reg) * 72 + sub * 16 + l16] = h2u((_Float16)p);
            }

        // PV + row-sum via ones-MFMA (ls4 in same C-layout as o_acc)
        f16x8 a0 = *(const f16x8*)&Pl[l16 * 72 + quad * 8];
        f16x8 a1 = *(const f16x8*)&Pl[l16 * 72 + 32 + quad * 8];
        __builtin_amdgcn_s_setprio(1);
        ls4 = __builtin_amdgcn_mfma_f32_16x16x32_f16(a0, ones, ls4, 0, 0, 0);
        ls4 = __builtin_amdgcn_mfma_f32_16x16x32_f16(a1, ones, ls4, 0, 0, 0);
        #pragma unroll
        for (int sub = 0; sub < 4; ++sub) {
            f16x8 bb0 = *(const f16x8*)&Vt[sub * 16 + l16][quad * 8];
            o_acc[sub] = __builtin_amdgcn_mfma_f32_16x16x32_f16(a0, bb0, o_acc[sub], 0, 0, 0);
            f16x8 bb1 = *(const f16x8*)&Vt[sub * 16 + l16][32 + quad * 8];
            o_acc[sub] = __builtin_amdgcn_mfma_f32_16x16x32_f16(a1, bb1, o_acc[sub], 0, 0, 0);
        }
        __builtin_amdgcn_s_setprio(0);
    }

    #pragma unroll
    for (int reg = 0; reg < 4; ++reg) {
        float inv = 1.f / ls4[reg];
        int qg = q0 + wave * 16 + quad * 4 + reg;
        ushort_t* orow = aout + ((long)(b * Q_ + qg)) * 1024 + h * 64;
        #pragma unroll
        for (int sub = 0; sub < 4; ++sub)
            orow[sub * 16 + l16] = h2u((_Float16)(o_acc[sub][reg] * inv));
    }
}

extern "C" void kernel_launch(void* const* d_in, const int* in_sizes, int n_in,
                              void* d_out, int out_size, void* d_ws, size_t ws_size,
                              hipStream_t stream) {
    const float* query  = (const float*)d_in[0];
    const float* memory = (const float*)d_in[1];
    const float* pos    = (const float*)d_in[2];
    // d_in[3] token_mask: analytic causal mask
    const float* cb  = (const float*)d_in[4];
    const float* pb  = (const float*)d_in[5];
    const float* Wq  = (const float*)d_in[6];
    const float* Wkc = (const float*)d_in[7];
    const float* Wkp = (const float*)d_in[8];
    const float* Wv  = (const float*)d_in[9];
    const float* Wo  = (const float*)d_in[10];
    float* out = (float*)d_out;
    ushort_t* ws = (ushort_t*)d_ws;

    size_t ws_elems = ws_size / 2;
    if (ws_elems < 36 * MEG) {
        zero_out_f32_k<<<(out_size + 255) / 256, 256, 0, stream>>>(out, out_size);
        return;
    }

    ushort_t* cbpb  = ws;                 // 1 MEG block (2048 used)
    ushort_t* BT4   = ws + MEG;           // 4 MEG stacked [Wkc;Wv;Wkp;Wq]^T
    ushort_t* WoT   = BT4 + 4 * MEG;      // 1 MEG
    ushort_t* kpp   = WoT + MEG;          // 1 MEG
    ushort_t* posb  = kpp + MEG;          // 1 MEG
    ushort_t* qproj = posb + MEG;         // 4 MEG
    ushort_t* kcC   = qproj + 4 * MEG;    // 8 MEG dense [B,R,1024]
    ushort_t* vT    = kcC + 8 * MEG;      // 8 MEG [B,1024(hs),1024(r)]
    ushort_t* qcat  = vT + 8 * MEG;       // 8 MEG (total 36 MEG)
    ushort_t* aout  = qproj;              // alias: attn blocks read-then-write own region

    // 4 launches total
    prep_k<<<dim3(1024, 15), 256, 0, stream>>>(
        memory, query, pos, cb, pb, Wkc, Wv, Wkp, Wq, Wo,
        qcat, posb, cbpb, BT4, WoT);
    gemm_mega<<<dim3(1344), 256, 0, stream>>>(qcat, posb, BT4, kcC, vT, qproj, kpp);
    attn_kernel<<<dim3(4, 128), 512, 0, stream>>>(qproj, kcC, kpp, vT, cbpb, aout);
    gemm_fin<<<dim3(32, 8, 1), 256, 0, stream>>>(aout, WoT, out);
}

// Round 14
// 243.967 us; speedup vs baseline: 1.0345x; 1.0345x over previous
//
#include <hip/hip_runtime.h>

#define B_ 8
#define Q_ 512
#define M_ 512
#define R_ 1024
#define H_ 16
#define S_ 64
#define D_ 1024
#define MEG 1048576L

typedef unsigned short ushort_t;
typedef __attribute__((ext_vector_type(8))) _Float16 f16x8;
typedef __attribute__((ext_vector_type(8))) unsigned short u16x8;
typedef __attribute__((ext_vector_type(4))) unsigned short u16x4;
typedef __attribute__((ext_vector_type(4))) float f32x4;
typedef __attribute__((ext_vector_type(2))) unsigned int u32x2;

__device__ __forceinline__ unsigned short h2u(_Float16 h) {
    union { _Float16 h; unsigned short u; } v; v.h = h; return v.u;
}
__device__ __forceinline__ unsigned int pk_f16(float a, float b) {
    union { _Float16 h[2]; unsigned int u; } v;
    v.h[0] = (_Float16)a; v.h[1] = (_Float16)b; return v.u;
}
__device__ __forceinline__ void async_cp16(const ushort_t* g, ushort_t* l) {
    __builtin_amdgcn_global_load_lds(
        (const __attribute__((address_space(1))) void*)g,
        (__attribute__((address_space(3))) void*)l, 16, 0, 0);
}

__global__ __launch_bounds__(256) void zero_out_f32_k(float* __restrict__ p, int n) {
    int i = blockIdx.x * 256 + threadIdx.x;
    if (i < n) p[i] = 0.f;
}

// ---- fused prep: weight transposes (y<5), qcat convert (y in [5,13)),
// ---- pos convert (y==13), bias convert (y==14) ----
__global__ __launch_bounds__(256) void prep_k(
    const float* __restrict__ mem, const float* __restrict__ qry,
    const float* __restrict__ pos, const float* __restrict__ cb,
    const float* __restrict__ pb,
    const float* __restrict__ Wkc, const float* __restrict__ Wv,
    const float* __restrict__ Wkp, const float* __restrict__ Wq,
    const float* __restrict__ Wo,
    ushort_t* __restrict__ qcat, ushort_t* __restrict__ posb,
    ushort_t* __restrict__ cbpb, ushort_t* __restrict__ BT4,
    ushort_t* __restrict__ WoT) {
    int x = blockIdx.x, y = blockIdx.y, t = threadIdx.x;
    if (y < 5) {   // weight transpose: fp32 W[k][n] -> f16 W^T[n][k]
        const float* in; ushort_t* out;
        switch (y) {
            case 0: in = Wkc; out = BT4;           break;
            case 1: in = Wv;  out = BT4 + MEG;     break;
            case 2: in = Wkp; out = BT4 + 2 * MEG; break;
            case 3: in = Wq;  out = BT4 + 3 * MEG; break;
            default: in = Wo; out = WoT;           break;
        }
        __shared__ ushort_t tile[32][33];
        int bx = (x & 31) * 32, by = (x >> 5) * 32;
        int tx = t & 31, ty = t >> 5;
        #pragma unroll
        for (int i = 0; i < 32; i += 8)
            tile[ty + i][tx] = h2u((_Float16)in[(long)(by + ty + i) * 1024 + bx + tx]);
        __syncthreads();
        #pragma unroll
        for (int i = 0; i < 32; i += 8)
            out[(long)(bx + ty + i) * 1024 + by + tx] = tile[tx][ty + i];
    } else if (y < 13) {  // qcat rows: batch g, row r
        int g = y - 5, r = x;
        const float* src = (r < 512) ? (mem + ((long)g * 512 + r) * 1024)
                                     : (qry + ((long)g * 512 + (r - 512)) * 1024);
        ushort_t* dst = qcat + ((long)g * 1024 + r) * 1024;
        int i = t * 4;
        f32x4 v = *(const f32x4*)(src + i);
        u32x2 o; o[0] = pk_f16(v[0], v[1]); o[1] = pk_f16(v[2], v[3]);
        *(u32x2*)(dst + i) = o;
    } else if (y == 13) { // pos rows
        int i = t * 4;
        f32x4 v = *(const f32x4*)(pos + (long)x * 1024 + i);
        u32x2 o; o[0] = pk_f16(v[0], v[1]); o[1] = pk_f16(v[2], v[3]);
        *(u32x2*)(posb + (long)x * 1024 + i) = o;
    } else {              // biases (x==0 only)
        if (x == 0) {
            for (int i = t; i < 1024; i += 256) {
                cbpb[i]        = h2u((_Float16)cb[i]);
                cbpb[1024 + i] = h2u((_Float16)pb[i]);
            }
        }
    }
}

// ---- GEMM body: 128x128 tile, K=1024, f16 MFMA, double-buffered LDS with
// ---- prefetch-before-compute (T3 minimum 2-phase): STAGE(next) -> ds_read(cur)
// ---- -> MFMA -> one __syncthreads() per step (implicit vmcnt(0)+lgkmcnt(0)).
// ---- PROVEN BEST (r7/r11: 67.5-69 us, ~668 TF). FOUR perturbations all
// ---- regressed: r8 3-buf rolled (+5), r9 8-wave BK=64 (+44), r10 3-buf
// ---- literal (+17), r13 BK=64+swizzle (+21; conflicts 5.5M->0 proved
// ---- conflicts immaterial -- occupancy/block-TLP is the binding resource).
// ---- This 2-phase structure is the measured local optimum.
// mode 0: f16 store, row stride crs.  mode 1: f32 store, stride crs.
// mode 2: f16 transposed store into vT: addr = n_local*1024 + m_local (Crow0 pre-offset)
__device__ __forceinline__ void gemm_body(const ushort_t* Arow0,
                                          const ushort_t* BTrow0,
                                          void* Crow0, long crs, int mode) {
    __shared__ __align__(16) ushort_t Al[2][128 * 32];   // packed 64B rows, dbuf
    __shared__ __align__(16) ushort_t Bl[2][128 * 32];

    int t = threadIdx.x;
    int wave = t >> 6, lane = t & 63, quad = lane >> 4, l16 = lane & 15;
    int wm = (wave & 1) * 64, wn = (wave >> 1) * 64;

    f32x4 acc[4][4];
    #pragma unroll
    for (int im = 0; im < 4; ++im)
        #pragma unroll
        for (int in = 0; in < 4; ++in) acc[im][in] = (f32x4){0.f, 0.f, 0.f, 0.f};

    // async staging: group (wave*2+i) covers tile rows [(wave*2+i)*16,+16);
    // lane covers row +(lane>>2), k-chunk (lane&3)*8.
    // LDS dest = wave-uniform base + lane*16B -> conflict-free sequential 1KB.
    int grow = lane >> 2, gcol = (lane & 3) * 8;
    const ushort_t* ga0 = Arow0 + (long)(wave * 32 + grow) * 1024 + gcol;
    const ushort_t* ga1 = Arow0 + (long)(wave * 32 + 16 + grow) * 1024 + gcol;
    const ushort_t* gb0 = BTrow0 + (long)(wave * 32 + grow) * 1024 + gcol;
    const ushort_t* gb1 = BTrow0 + (long)(wave * 32 + 16 + grow) * 1024 + gcol;
    int lo0 = (wave * 2 + 0) * 512;
    int lo1 = (wave * 2 + 1) * 512;

    // prologue: stage k0=0 into buf 0; __syncthreads drains vmcnt(0)
    async_cp16(ga0, &Al[0][lo0]);
    async_cp16(ga1, &Al[0][lo1]);
    async_cp16(gb0, &Bl[0][lo0]);
    async_cp16(gb1, &Bl[0][lo1]);
    __syncthreads();

    int cur = 0;
    for (int k0 = 0; k0 < 1024; k0 += 32) {
        int nxt = cur ^ 1;
        if (k0 + 32 < 1024) {   // issue next-tile loads FIRST (latency overlap)
            async_cp16(ga0 + k0 + 32, &Al[nxt][lo0]);
            async_cp16(ga1 + k0 + 32, &Al[nxt][lo1]);
            async_cp16(gb0 + k0 + 32, &Bl[nxt][lo0]);
            async_cp16(gb1 + k0 + 32, &Bl[nxt][lo1]);
        }

        f16x8 af[4], bf[4];
        #pragma unroll
        for (int im = 0; im < 4; ++im)
            af[im] = *(const f16x8*)&Al[cur][(wm + im * 16 + l16) * 32 + quad * 8];
        #pragma unroll
        for (int in = 0; in < 4; ++in)
            bf[in] = *(const f16x8*)&Bl[cur][(wn + in * 16 + l16) * 32 + quad * 8];
        __builtin_amdgcn_s_setprio(1);
        #pragma unroll
        for (int im = 0; im < 4; ++im)
            #pragma unroll
            for (int in = 0; in < 4; ++in)
                acc[im][in] = __builtin_amdgcn_mfma_f32_16x16x32_f16(
                    af[im], bf[in], acc[im][in], 0, 0, 0);
        __builtin_amdgcn_s_setprio(0);
        __syncthreads();   // drains this step's staging; next buf ready
        cur = nxt;
    }

    if (mode == 2) {   // transposed store (v -> vT): rows = n (hs), cols = m (r)
        #pragma unroll
        for (int im = 0; im < 4; ++im)
            #pragma unroll
            for (int in = 0; in < 4; ++in) {
                u16x4 pk;
                #pragma unroll
                for (int reg = 0; reg < 4; ++reg) pk[reg] = h2u((_Float16)acc[im][in][reg]);
                long addr = (long)(wn + in * 16 + l16) * 1024 + wm + im * 16 + quad * 4;
                *(u16x4*)((ushort_t*)Crow0 + addr) = pk;
            }
        return;
    }
    #pragma unroll
    for (int im = 0; im < 4; ++im)
        #pragma unroll
        for (int in = 0; in < 4; ++in)
            #pragma unroll
            for (int reg = 0; reg < 4; ++reg) {
                long addr = (long)(wm + im * 16 + quad * 4 + reg) * crs
                          + wn + in * 16 + l16;
                if (mode == 1) ((float*)Crow0)[addr] = acc[im][in][reg];
                else ((ushort_t*)Crow0)[addr] = h2u((_Float16)acc[im][in][reg]);
            }
}

// ---- mega projection GEMM, flat grid of exactly 1344 tiles:
// ---- [0,1024): kc/vT (z=id>>7, tl=id&127, x=tl>>4, y=tl&15)
// ---- [1024,1088): kp.  [1088,1344): qproj.
// XCD mapping: id%8 = y&7 -> each XCD holds 2 B-panels (0.5 MB) + A-slice (2 MB) in L2.
__global__ __launch_bounds__(256) void gemm_mega(
    const ushort_t* __restrict__ qcat, const ushort_t* __restrict__ posb,
    const ushort_t* __restrict__ BT4,
    ushort_t* __restrict__ kcC, ushort_t* __restrict__ vT,
    ushort_t* __restrict__ qproj, ushort_t* __restrict__ kpp) {
    int id = blockIdx.x;
    if (id < 1024) {
        int z = id >> 7, tl = id & 127;
        int x = tl >> 4, y = tl & 15;
        const ushort_t* Arow0 = qcat + (long)z * MEG + (long)x * 128 * 1024;
        if (y < 8) {        // kc: dense [B,R,1024]
            gemm_body(Arow0, BT4 + (long)y * 128 * 1024,
                      kcC + (long)z * MEG + (long)x * 128 * 1024 + y * 128, 1024, 0);
        } else {            // v: store transposed into vT [B,1024(hs),1024(r)]
            int n0 = (y - 8) * 128;
            gemm_body(Arow0, BT4 + (long)(1024 + n0) * 1024,
                      vT + ((long)z * 1024 + n0) * 1024 + x * 128, 0, 2);
        }
    } else if (id < 1088) { // kp = posb @ Wkp
        int u = id - 1024;
        int x = u >> 3, y = u & 7;
        gemm_body(posb + (long)x * 128 * 1024,
                  BT4 + (long)(2048 + y * 128) * 1024,
                  kpp + (long)x * 128 * 1024 + y * 128, 1024, 0);
    } else {                // qproj[b] = qcat[b][512..1023] @ Wq
        int u = id - 1088;
        int b = u >> 5, v2 = u & 31;
        int x = v2 >> 3, y = v2 & 7;
        gemm_body(qcat + (long)b * MEG + (long)(512 + x * 128) * 1024,
                  BT4 + (long)(3072 + y * 128) * 1024,
                  qproj + (long)b * 512 * 1024 + (long)x * 128 * 1024 + y * 128, 1024, 0);
    }
}

__global__ __launch_bounds__(256) void gemm_fin(
    const ushort_t* __restrict__ A, const ushort_t* __restrict__ WoT,
    float* __restrict__ out) {
    gemm_body(A + (long)blockIdx.x * 128 * 1024,
              WoT + (long)blockIdx.y * 128 * 1024,
              out + (long)blockIdx.x * 128 * 1024 + blockIdx.y * 128, 1024, 1);
}

// ---- fused relative attention: 128-q-tile, 8 waves, software-pipelined staging ----
// LDS: Kc 9216 + Vt 9216 + Kp 27648 + Pu 18432 = 64512 B -> 2 blocks/CU.
// Row-sum via ones-MFMA; defer-max with thread-local check (shfl reduce rare).
__global__ __launch_bounds__(512) void attn_kernel(
    const ushort_t* __restrict__ qproj,  // [B,Q,1024] f16
    const ushort_t* __restrict__ kc,     // [B,R,1024] f16 (dense)
    const ushort_t* __restrict__ kp,     // [R,1024] f16
    const ushort_t* __restrict__ vT,     // [B,1024,R] f16
    const ushort_t* __restrict__ cbpb,   // [2,16,64] f16
    ushort_t* __restrict__ aout)         // [B,Q,1024] f16 (aliases qproj; safe)
{
    // load-balance swizzle: co-resident blocks (ID, ID+256) -> classes (c, c+2)
    int qt = (blockIdx.x + ((blockIdx.y >> 6) << 1)) & 3;
    int q0 = qt * 128;
    int bh = blockIdx.y;
    int b = bh >> 4, h = bh & 15;
    int t = threadIdx.x;
    int wave = t >> 6, lane = t & 63, quad = lane >> 4, l16 = lane & 15;

    __shared__ __align__(16) ushort_t Kc[64][72];
    __shared__ __align__(16) ushort_t Vt[64][72];
    __shared__ __align__(16) ushort_t Kp[192][72];   // 12 circular 16-row blocks
    __shared__ __align__(16) char Pu[8][2304];       // Pl[16][72] u16 per wave
    ushort_t* Pl = (ushort_t*)&Pu[wave][0];

    const ushort_t* qrow = qproj + ((long)(b * Q_ + q0 + wave * 16 + l16)) * 1024 + h * 64;
    f16x8 qcf[2], qpf[2];
    #pragma unroll
    for (int ks = 0; ks < 2; ++ks) {
        f16x8 qv  = *(const f16x8*)(qrow + ks * 32 + quad * 8);
        f16x8 cbv = *(const f16x8*)(cbpb + h * 64 + ks * 32 + quad * 8);
        f16x8 pbv = *(const f16x8*)(cbpb + 1024 + h * 64 + ks * 32 + quad * 8);
        qcf[ks] = qv + cbv;
        qpf[ks] = qv + pbv;
    }

    float m_s[4];
    f32x4 o_acc[4], ls4;
    #pragma unroll
    for (int r = 0; r < 4; ++r) {
        m_s[r] = -1e30f;
        o_acc[r] = (f32x4){0.f, 0.f, 0.f, 0.f};
    }
    ls4 = (f32x4){0.f, 0.f, 0.f, 0.f};

    f16x8 ones;
    #pragma unroll
    for (int j = 0; j < 8; ++j) ones[j] = (_Float16)1.0f;

    int srow = t >> 3, sc0 = (t & 7) * 8;
    const ushort_t* kcb = kc + ((long)(b * R_) + srow) * 1024 + h * 64 + sc0;
    const ushort_t* vtb = vT + ((long)(b * 1024 + h * 64 + srow)) * 1024 + sc0;
    const ushort_t* kpb = kp + h * 64 + sc0;

    int ntiles = ((q0 + 639) >> 6) + 1;  // causal: last q-row attends r <= q0+639

    // pipeline prologue: iter-0 staging in registers
    u16x8 rKc = *(const u16x8*)(kcb);
    u16x8 rVt = *(const u16x8*)(vtb);
    u16x8 rKp[3];
    {
        int jb0 = 384 - q0;
        #pragma unroll
        for (int p = 0; p < 3; ++p) {
            int j = jb0 + p * 64 + srow;
            int jc = j > 1023 ? 1023 : j;
            rKp[p] = *(const u16x8*)(kpb + (long)jc * 1024);
        }
    }

    for (int it = 0; it < ntiles; ++it) {
        int r0 = it * 64;
        int jbase = r0 - q0 + 384;
        int gb0 = jbase >> 4;
        __syncthreads();
        *(u16x8*)&Kc[srow][sc0] = rKc;
        *(u16x8*)&Vt[srow][sc0] = rVt;
        if (it == 0) {
            #pragma unroll
            for (int p = 0; p < 3; ++p) {
                int j = jbase + p * 64 + srow;
                int ph = ((j >> 4) % 12) * 16 + (j & 15);
                *(u16x8*)&Kp[ph][sc0] = rKp[p];
            }
        } else {
            int j = jbase + 128 + srow;
            int ph = ((j >> 4) % 12) * 16 + (j & 15);
            *(u16x8*)&Kp[ph][sc0] = rKp[0];
        }
        __syncthreads();
        if (it + 1 < ntiles) {
            int r1 = r0 + 64;
            rKc = *(const u16x8*)(kcb + (long)r1 * 1024);
            rVt = *(const u16x8*)(vtb + r1);
            int j = r1 - q0 + 512 + srow;
            int jc = j > 1023 ? 1023 : j;
            rKp[0] = *(const u16x8*)(kpb + (long)jc * 1024);
        }

        f32x4 sc[4];
        #pragma unroll
        for (int s = 0; s < 4; ++s) sc[s] = (f32x4){0.f, 0.f, 0.f, 0.f};
        f32x4 dd[5];
        #pragma unroll
        for (int s = 0; s < 5; ++s) dd[s] = (f32x4){0.f, 0.f, 0.f, 0.f};

        __builtin_amdgcn_s_setprio(1);
        #pragma unroll
        for (int ks = 0; ks < 2; ++ks)
            #pragma unroll
            for (int sub = 0; sub < 4; ++sub) {
                f16x8 bb = *(const f16x8*)&Kc[sub * 16 + l16][ks * 32 + quad * 8];
                sc[sub] = __builtin_amdgcn_mfma_f32_16x16x32_f16(qcf[ks], bb, sc[sub], 0, 0, 0);
            }
        #pragma unroll
        for (int ks = 0; ks < 2; ++ks)
            #pragma unroll
            for (int sub = 0; sub < 5; ++sub) {
                int pb = (gb0 + 7 - wave + sub) % 12;
                f16x8 bb = *(const f16x8*)&Kp[pb * 16 + l16][ks * 32 + quad * 8];
                dd[sub] = __builtin_amdgcn_mfma_f32_16x16x32_f16(qpf[ks], bb, dd[sub], 0, 0, 0);
            }
        __builtin_amdgcn_s_setprio(0);

        // rel-shift diagonal extraction IN-REGISTER (proven r1-r13).
        #pragma unroll
        for (int reg = 0; reg < 4; ++reg) {
            int row16 = quad * 4 + reg;
            int src = (lane & 48) + ((l16 + 15 - row16) & 15);
            float dsh[5];
            #pragma unroll
            for (int sub = 0; sub < 5; ++sub)
                dsh[sub] = __shfl(dd[sub][reg], src);
            #pragma unroll
            for (int sub = 0; sub < 4; ++sub) {
                float dval = (l16 > row16) ? dsh[sub + 1] : dsh[sub];
                float sv = (sc[sub][reg] + dval) * 0.125f;
                int rl = sub * 16 + l16;
                if (r0 + rl > q0 + wave * 16 + row16 + 512) sv = -1e30f;
                sc[sub][reg] = sv;
            }
        }

        // T13 defer-max with CHEAP check (shfl reduce only on rare fail path).
        float vmax[4];
        #pragma unroll
        for (int reg = 0; reg < 4; ++reg)
            vmax[reg] = fmaxf(fmaxf(sc[0][reg], sc[1][reg]),
                              fmaxf(sc[2][reg], sc[3][reg]));
        int ok = (vmax[0] <= m_s[0] + 8.f) & (vmax[1] <= m_s[1] + 8.f) &
                 (vmax[2] <= m_s[2] + 8.f) & (vmax[3] <= m_s[3] + 8.f);
        if (!__all(ok)) {
            #pragma unroll
            for (int reg = 0; reg < 4; ++reg) {
                float rm = vmax[reg];
                #pragma unroll
                for (int m = 1; m < 16; m <<= 1) rm = fmaxf(rm, __shfl_xor(rm, m));
                float mn = fmaxf(m_s[reg], rm);
                float alpha = __expf(m_s[reg] - mn);
                m_s[reg] = mn;
                ls4[reg] *= alpha;
                #pragma unroll
                for (int sub = 0; sub < 4; ++sub)
                    o_acc[sub][reg] *= alpha;
            }
        }
        #pragma unroll
        for (int sub = 0; sub < 4; ++sub)
            #pragma unroll
            for (int reg = 0; reg < 4; ++reg) {
                float p = __expf(sc[sub][reg] - m_s[reg]);
                Pl[(quad * 4 + reg) * 72 + sub * 16 + l16] = h2u((_Float16)p);
            }

        // PV + row-sum via ones-MFMA (ls4 in same C-layout as o_acc)
        f16x8 a0 = *(const f16x8*)&Pl[l16 * 72 + quad * 8];
        f16x8 a1 = *(const f16x8*)&Pl[l16 * 72 + 32 + quad * 8];
        __builtin_amdgcn_s_setprio(1);
        ls4 = __builtin_amdgcn_mfma_f32_16x16x32_f16(a0, ones, ls4, 0, 0, 0);
        ls4 = __builtin_amdgcn_mfma_f32_16x16x32_f16(a1, ones, ls4, 0, 0, 0);
        #pragma unroll
        for (int sub = 0; sub < 4; ++sub) {
            f16x8 bb0 = *(const f16x8*)&Vt[sub * 16 + l16][quad * 8];
            o_acc[sub] = __builtin_amdgcn_mfma_f32_16x16x32_f16(a0, bb0, o_acc[sub], 0, 0, 0);
            f16x8 bb1 = *(const f16x8*)&Vt[sub * 16 + l16][32 + quad * 8];
            o_acc[sub] = __builtin_amdgcn_mfma_f32_16x16x32_f16(a1, bb1, o_acc[sub], 0, 0, 0);
        }
        __builtin_amdgcn_s_setprio(0);
    }

    #pragma unroll
    for (int reg = 0; reg < 4; ++reg) {
        float inv = 1.f / ls4[reg];
        int qg = q0 + wave * 16 + quad * 4 + reg;
        ushort_t* orow = aout + ((long)(b * Q_ + qg)) * 1024 + h * 64;
        #pragma unroll
        for (int sub = 0; sub < 4; ++sub)
            orow[sub * 16 + l16] = h2u((_Float16)(o_acc[sub][reg] * inv));
    }
}

extern "C" void kernel_launch(void* const* d_in, const int* in_sizes, int n_in,
                              void* d_out, int out_size, void* d_ws, size_t ws_size,
                              hipStream_t stream) {
    const float* query  = (const float*)d_in[0];
    const float* memory = (const float*)d_in[1];
    const float* pos    = (const float*)d_in[2];
    // d_in[3] token_mask: analytic causal mask
    const float* cb  = (const float*)d_in[4];
    const float* pb  = (const float*)d_in[5];
    const float* Wq  = (const float*)d_in[6];
    const float* Wkc = (const float*)d_in[7];
    const float* Wkp = (const float*)d_in[8];
    const float* Wv  = (const float*)d_in[9];
    const float* Wo  = (const float*)d_in[10];
    float* out = (float*)d_out;
    ushort_t* ws = (ushort_t*)d_ws;

    size_t ws_elems = ws_size / 2;
    if (ws_elems < 36 * MEG) {
        zero_out_f32_k<<<(out_size + 255) / 256, 256, 0, stream>>>(out, out_size);
        return;
    }

    ushort_t* cbpb  = ws;                 // 1 MEG block (2048 used)
    ushort_t* BT4   = ws + MEG;           // 4 MEG stacked [Wkc;Wv;Wkp;Wq]^T
    ushort_t* WoT   = BT4 + 4 * MEG;      // 1 MEG
    ushort_t* kpp   = WoT + MEG;          // 1 MEG
    ushort_t* posb  = kpp + MEG;          // 1 MEG
    ushort_t* qproj = posb + MEG;         // 4 MEG
    ushort_t* kcC   = qproj + 4 * MEG;    // 8 MEG dense [B,R,1024]
    ushort_t* vT    = kcC + 8 * MEG;      // 8 MEG [B,1024(hs),1024(r)]
    ushort_t* qcat  = vT + 8 * MEG;       // 8 MEG (total 36 MEG)
    ushort_t* aout  = qproj;              // alias: attn blocks read-then-write own region

    // 4 launches total
    prep_k<<<dim3(1024, 15), 256, 0, stream>>>(
        memory, query, pos, cb, pb, Wkc, Wv, Wkp, Wq, Wo,
        qcat, posb, cbpb, BT4, WoT);
    gemm_mega<<<dim3(1344), 256, 0, stream>>>(qcat, posb, BT4, kcC, vT, qproj, kpp);
    attn_kernel<<<dim3(4, 128), 512, 0, stream>>>(qproj, kcC, kpp, vT, cbpb, aout);
    gemm_fin<<<dim3(32, 8, 1), 256, 0, stream>>>(aout, WoT, out);
}